// Round 2
// baseline (1497.580 us; speedup 1.0000x reference)
//
#include <hip/hip_runtime.h>

typedef float f4 __attribute__((ext_vector_type(4)));

constexpr int En  = 1024;
constexpr int Wn  = 1024;
constexpr int Bn  = 8;
constexpr int Hn  = 16;
constexpr int DHn = 64;

// ---------------------------------------------------------------------------
// Batched GEMM: Y[b] = L @ X[b] (+ bias), L:[E,E], X:[E,W], row-major fp32.
// grid (W/128, E/128, nbatch), block 256. 128x128 tile, 8x8 per thread.
// ---------------------------------------------------------------------------
__global__ __launch_bounds__(256, 2)
void gemm128(const float* __restrict__ L, const float* __restrict__ X,
             float* __restrict__ Y, const float* __restrict__ bias) {
    __shared__ float As[16][132];   // As[f][e]   (A tile transposed)
    __shared__ float Bs[16][132];   // Bs[f][w]

    const int bz = blockIdx.z;
    const float* Xb = X + (size_t)bz * En * Wn;
    float*       Yb = Y + (size_t)bz * En * Wn;
    const int e0 = blockIdx.y * 128;
    const int w0 = blockIdx.x * 128;
    const int t  = threadIdx.x;
    const int tx = t & 15, ty = t >> 4;
    const int la_e = t >> 2, la_f = (t & 3) << 2;   // A: 128 rows x 16 cols
    const int lb_f = t >> 5, lb_w = (t & 31) << 2;  // B: 16 rows x 128 cols

    float acc[2][2][4][4] = {};     // [ehalf][whalf][i][j]

    for (int f0 = 0; f0 < En; f0 += 16) {
        f4 a0 = *(const f4*)&L [(size_t)(e0 + la_e)      * En + f0 + la_f];
        f4 a1 = *(const f4*)&L [(size_t)(e0 + la_e + 64) * En + f0 + la_f];
        f4 b0 = *(const f4*)&Xb[(size_t)(f0 + lb_f)      * Wn + w0 + lb_w];
        f4 b1 = *(const f4*)&Xb[(size_t)(f0 + lb_f + 8)  * Wn + w0 + lb_w];
        __syncthreads();
        As[la_f + 0][la_e] = a0[0]; As[la_f + 1][la_e] = a0[1];
        As[la_f + 2][la_e] = a0[2]; As[la_f + 3][la_e] = a0[3];
        As[la_f + 0][la_e + 64] = a1[0]; As[la_f + 1][la_e + 64] = a1[1];
        As[la_f + 2][la_e + 64] = a1[2]; As[la_f + 3][la_e + 64] = a1[3];
        *(f4*)&Bs[lb_f    ][lb_w] = b0;
        *(f4*)&Bs[lb_f + 8][lb_w] = b1;
        __syncthreads();
        #pragma unroll
        for (int kk = 0; kk < 16; ++kk) {
            f4 av0 = *(f4*)&As[kk][ty * 4];
            f4 av1 = *(f4*)&As[kk][ty * 4 + 64];
            f4 bv0 = *(f4*)&Bs[kk][tx * 4];
            f4 bv1 = *(f4*)&Bs[kk][tx * 4 + 64];
            #pragma unroll
            for (int i = 0; i < 4; ++i)
                #pragma unroll
                for (int j = 0; j < 4; ++j) {
                    acc[0][0][i][j] = fmaf(av0[i], bv0[j], acc[0][0][i][j]);
                    acc[0][1][i][j] = fmaf(av0[i], bv1[j], acc[0][1][i][j]);
                    acc[1][0][i][j] = fmaf(av1[i], bv0[j], acc[1][0][i][j]);
                    acc[1][1][i][j] = fmaf(av1[i], bv1[j], acc[1][1][i][j]);
                }
        }
    }

    #pragma unroll
    for (int eh = 0; eh < 2; ++eh)
        #pragma unroll
        for (int i = 0; i < 4; ++i) {
            const int e = e0 + eh * 64 + ty * 4 + i;
            const float bv = bias ? bias[e] : 0.0f;
            #pragma unroll
            for (int wh = 0; wh < 2; ++wh) {
                f4 v;
                #pragma unroll
                for (int j = 0; j < 4; ++j) v[j] = acc[eh][wh][i][j] + bv;
                *(f4*)&Yb[(size_t)e * Wn + w0 + wh * 64 + tx * 4] = v;
            }
        }
}

// ---------------------------------------------------------------------------
// Flash attention, softmax over q (query axis), causal mask q <= k.
// out[d,k] = (1/32) * sum_{q<=k} softmax_q( sum_d' Q[d',q]K[d',k] ) * V[d,q]
// grid (W/64, H, B), block 256. One block owns 64 k-columns of one (b,h).
// ---------------------------------------------------------------------------
__global__ __launch_bounds__(256, 2)
void attn64(const float* __restrict__ Qg, const float* __restrict__ Kg,
            const float* __restrict__ Vg, float* __restrict__ Og) {
    __shared__ float Ks[64][68];    // Ks[d][kc]
    __shared__ float QP[64][68];    // Q tile Qs[d][q], then reused as P[q][kc]
    __shared__ float Vt[64][68];    // V transposed: Vt[q][d]
    __shared__ float mArr[64], lArr[64], alphaArr[64];
    __shared__ float red[4][64];

    const int kb = blockIdx.x, h = blockIdx.y, b = blockIdx.z;
    const size_t base = ((size_t)b * En + (size_t)h * DHn) * Wn;
    const float* Qp = Qg + base;
    const float* Kp = Kg + base;
    const float* Vp = Vg + base;
    float*       Op = Og + base;

    const int t  = threadIdx.x;
    const int tx = t & 15, ty = t >> 4;
    const int lr = t >> 4;          // loader row base: 0..15 (+16*r)
    const int lc = (t & 15) << 2;   // loader col: 0..60
    const int k0 = kb * 64;
    const int kc = t & 63, qg = t >> 6;

    // load full 64x64 K tile: 4 rows per thread
    #pragma unroll
    for (int r = 0; r < 4; ++r)
        *(f4*)&Ks[lr + r * 16][lc] =
            *(const f4*)&Kp[(size_t)(lr + r * 16) * Wn + k0 + lc];
    if (t < 64) { mArr[t] = -1e30f; lArr[t] = 0.0f; }
    float acc[4][4] = {};           // O[d = ty*4+i][kc = tx*4+j]
    __syncthreads();

    for (int q0 = 0; q0 <= k0; q0 += 64) {
        #pragma unroll
        for (int r = 0; r < 4; ++r) {
            const int d = lr + r * 16;
            f4 qv = *(const f4*)&Qp[(size_t)d * Wn + q0 + lc];
            f4 vv = *(const f4*)&Vp[(size_t)d * Wn + q0 + lc];
            *(f4*)&QP[d][lc] = qv;
            Vt[lc + 0][d] = vv[0]; Vt[lc + 1][d] = vv[1];
            Vt[lc + 2][d] = vv[2]; Vt[lc + 3][d] = vv[3];
        }
        __syncthreads();

        // ---- S = K^T(cols) . Q(cols): s[q=ty*4+i][k=tx*4+j]
        float s[4][4] = {};
        #pragma unroll 4
        for (int d = 0; d < 64; ++d) {
            f4 kv = *(f4*)&Ks[d][tx * 4];
            f4 q2 = *(f4*)&QP[d][ty * 4];
            #pragma unroll
            for (int i = 0; i < 4; ++i)
                #pragma unroll
                for (int j = 0; j < 4; ++j)
                    s[i][j] = fmaf(q2[i], kv[j], s[i][j]);
        }
        if (q0 == k0) {            // diagonal tile: mask q > k
            #pragma unroll
            for (int i = 0; i < 4; ++i)
                #pragma unroll
                for (int j = 0; j < 4; ++j)
                    if (ty * 4 + i > tx * 4 + j) s[i][j] = -1e30f;
        }
        __syncthreads();           // all Q reads done; QP becomes P
        #pragma unroll
        for (int i = 0; i < 4; ++i) {
            f4 v;
            #pragma unroll
            for (int j = 0; j < 4; ++j) v[j] = s[i][j];
            *(f4*)&QP[ty * 4 + i][tx * 4] = v;
        }
        __syncthreads();

        // ---- online softmax over q, per column kc (4 threads/column)
        float sv[16];
        float lm = -1e30f;
        #pragma unroll
        for (int r = 0; r < 16; ++r) {
            sv[r] = QP[qg * 16 + r][kc];
            lm = fmaxf(lm, sv[r]);
        }
        red[qg][kc] = lm;
        __syncthreads();
        const float mt    = fmaxf(fmaxf(red[0][kc], red[1][kc]),
                                  fmaxf(red[2][kc], red[3][kc]));
        const float mprev = mArr[kc];
        const float mnew  = fmaxf(mprev, mt);
        float psum = 0.0f;
        #pragma unroll
        for (int r = 0; r < 16; ++r) {
            const float p = __expf(sv[r] - mnew);
            psum += p;
            QP[qg * 16 + r][kc] = p;
        }
        __syncthreads();           // mt reads of red[] complete
        red[qg][kc] = psum;
        __syncthreads();
        if (qg == 0) {
            const float alpha = __expf(mprev - mnew);
            lArr[kc] = lArr[kc] * alpha +
                       (red[0][kc] + red[1][kc] + red[2][kc] + red[3][kc]);
            mArr[kc]     = mnew;
            alphaArr[kc] = alpha;
        }
        __syncthreads();

        // ---- PV: acc[d][kc] = acc*alpha + sum_q V[d,q] P[q,kc]
        f4 al = *(f4*)&alphaArr[tx * 4];
        #pragma unroll
        for (int i = 0; i < 4; ++i)
            #pragma unroll
            for (int j = 0; j < 4; ++j)
                acc[i][j] *= al[j];
        #pragma unroll 4
        for (int q = 0; q < 64; ++q) {
            f4 pv = *(f4*)&QP[q][tx * 4];
            f4 v2 = *(f4*)&Vt[q][ty * 4];
            #pragma unroll
            for (int i = 0; i < 4; ++i)
                #pragma unroll
                for (int j = 0; j < 4; ++j)
                    acc[i][j] = fmaf(v2[i], pv[j], acc[i][j]);
        }
        __syncthreads();           // before next iter overwrites QP/Vt
    }

    f4 linv = *(f4*)&lArr[tx * 4];
    #pragma unroll
    for (int j = 0; j < 4; ++j) linv[j] = 1.0f / (linv[j] * 32.0f);
    #pragma unroll
    for (int i = 0; i < 4; ++i) {
        f4 v;
        #pragma unroll
        for (int j = 0; j < 4; ++j) v[j] = acc[i][j] * linv[j];
        *(f4*)&Op[(size_t)(ty * 4 + i) * Wn + k0 + tx * 4] = v;
    }
}

// ---------------------------------------------------------------------------
extern "C" void kernel_launch(void* const* d_in, const int* in_sizes, int n_in,
                              void* d_out, int out_size, void* d_ws, size_t ws_size,
                              hipStream_t stream) {
    const float* x    = (const float*)d_in[0];   // [3,B,E,W]: x[0]=K, x[1]=Q, x[2]=V
    const float* L_Q  = (const float*)d_in[1];
    const float* L_K  = (const float*)d_in[2];
    const float* L_V  = (const float*)d_in[3];
    const float* M    = (const float*)d_in[4];
    const float* bias = (const float*)d_in[5];
    float* out = (float*)d_out;
    float* ws  = (float*)d_ws;

    const size_t mat = (size_t)Bn * En * Wn;     // 8M floats per [B,E,W] tensor
    float* Kp = ws;                              // projected K
    float* Qp = ws + mat;                        // projected Q
    float* Vp = ws + 2 * mat;                    // projected V
    float* Ao = ws + 3 * mat;                    // attention output

    dim3 gg(Wn / 128, En / 128, Bn), blk(256);
    hipLaunchKernelGGL(gemm128, gg, blk, 0, stream, L_K, x + 0 * mat, Kp, (const float*)nullptr);
    hipLaunchKernelGGL(gemm128, gg, blk, 0, stream, L_Q, x + 1 * mat, Qp, (const float*)nullptr);
    hipLaunchKernelGGL(gemm128, gg, blk, 0, stream, L_V, x + 2 * mat, Vp, (const float*)nullptr);

    dim3 ga(Wn / 64, Hn, Bn);
    hipLaunchKernelGGL(attn64, ga, blk, 0, stream, Qp, Kp, Vp, Ao);

    hipLaunchKernelGGL(gemm128, gg, blk, 0, stream, M, Ao, out, bias);
}

// Round 3
// 935.501 us; speedup vs baseline: 1.6008x; 1.6008x over previous
//
#include <hip/hip_runtime.h>

typedef float  f4  __attribute__((ext_vector_type(4)));
typedef short  s8v __attribute__((ext_vector_type(8)));   // 8 bf16 (4 VGPRs)
typedef unsigned short u16;
typedef u16 us4 __attribute__((ext_vector_type(4)));

constexpr int En  = 1024;
constexpr int Wn  = 1024;
constexpr int Bn  = 8;
constexpr int Hn  = 16;
constexpr int DHn = 64;

__device__ inline u16 bf16rn(float x) {
    unsigned u = __float_as_uint(x);
    return (u16)((u + 0x7FFFu + ((u >> 16) & 1u)) >> 16);
}
__device__ inline float bf16tof(u16 h) { return __uint_as_float(((unsigned)h) << 16); }

#define GLD_LDS16(gp, lp) __builtin_amdgcn_global_load_lds(                      \
    (const __attribute__((address_space(1))) void*)(gp),                         \
    (__attribute__((address_space(3))) void*)(lp), 16, 0, 0)

// ---------------------------------------------------------------------------
// Elementwise split: fp32 -> bf16 hi/lo. n4 = count of f4 groups.
// ---------------------------------------------------------------------------
__global__ void split_plain(const float* __restrict__ in, u16* __restrict__ hi,
                            u16* __restrict__ lo, int n4) {
    int i = blockIdx.x * blockDim.x + threadIdx.x;
    if (i >= n4) return;
    f4 v = ((const f4*)in)[i];
    us4 h, l;
    #pragma unroll
    for (int k = 0; k < 4; ++k) {
        u16 hh = bf16rn(v[k]);
        h[k] = hh;
        l[k] = bf16rn(v[k] - bf16tof(hh));
    }
    ((us4*)hi)[i] = h;
    ((us4*)lo)[i] = l;
}

// ---------------------------------------------------------------------------
// Transpose + split: in [z][1024][1024] fp32 -> hi/lo [z][1024][1024] bf16,
// out[c][r] = in[r][c]. grid (32, 32, NB), block 256.
// ---------------------------------------------------------------------------
__global__ __launch_bounds__(256)
void split_t(const float* __restrict__ in, u16* __restrict__ hi,
             u16* __restrict__ lo) {
    __shared__ float T[32][33];
    const int z = blockIdx.z;
    const size_t zo = (size_t)z * En * Wn;
    const int r0 = blockIdx.y * 32, c0 = blockIdx.x * 32;
    const int t = threadIdx.x;
    const int row = t >> 3, c4 = (t & 7) << 2;

    f4 v = *(const f4*)&in[zo + (size_t)(r0 + row) * Wn + c0 + c4];
    T[row][c4 + 0] = v[0]; T[row][c4 + 1] = v[1];
    T[row][c4 + 2] = v[2]; T[row][c4 + 3] = v[3];
    __syncthreads();

    const int oc = row, r4 = c4;       // reuse decomposition for output
    us4 h, l;
    #pragma unroll
    for (int i = 0; i < 4; ++i) {
        float x = T[r4 + i][oc];
        u16 hh = bf16rn(x);
        h[i] = hh;
        l[i] = bf16rn(x - bf16tof(hh));
    }
    *(us4*)&hi[zo + (size_t)(c0 + oc) * En + r0 + r4] = h;
    *(us4*)&lo[zo + (size_t)(c0 + oc) * En + r0 + r4] = l;
}

// ---------------------------------------------------------------------------
// MFMA GEMM with bf16 hi/lo split operands (3-term: hh + hl + lh).
// A  : [E][E] bf16 row-major (hi, lo)     -- the L / M matrix
// Bt : [z][W][E] bf16 (X transposed, so k is contiguous per row)
// Y  : [z][E][W] fp32.  grid (W/128, E/128, z), block 256 (4 waves).
// Wave computes 64x64 via 4x4 grid of 16x16x32 MFMAs; K-step 32.
// LDS chunk layout [m][g]: chunk index m*4+g, 16 B each -> bank-balanced
// b128 frag reads, 64 B-contiguous global segments for global_load_lds.
// ---------------------------------------------------------------------------
__global__ __launch_bounds__(256, 2)
void gemm_mfma(const u16* __restrict__ Ah,  const u16* __restrict__ Al,
               const u16* __restrict__ Bth, const u16* __restrict__ Btl,
               float* __restrict__ Y, const float* __restrict__ bias) {
    __shared__ u16 AsH[4096], AsL[4096], BsH[4096], BsL[4096]; // 512 chunks x 8

    const int z  = blockIdx.z;
    const size_t zB = (size_t)z * Wn * En;
    const size_t zY = (size_t)z * En * Wn;
    const int e0 = blockIdx.y * 128, n0 = blockIdx.x * 128;
    const int t = threadIdx.x, lane = t & 63, wave = t >> 6;
    const int q = lane >> 4, r = lane & 15;
    const int m_off = (wave & 1) * 64, n_off = (wave >> 1) * 64;

    f4 acc[4][4];
    #pragma unroll
    for (int i = 0; i < 4; ++i)
        #pragma unroll
        for (int j = 0; j < 4; ++j) { acc[i][j][0]=0; acc[i][j][1]=0; acc[i][j][2]=0; acc[i][j][3]=0; }

    for (int kb = 0; kb < En; kb += 32) {
        __syncthreads();
        #pragma unroll
        for (int it = 0; it < 2; ++it) {
            const int id = t + 256 * it;        // 0..511 chunk id = m*4+g
            const int m = id >> 2, g = id & 3;
            const size_t colA = (size_t)kb + 8 * g;
            const u16* ga_h = Ah  + (size_t)(e0 + m) * En + colA;
            const u16* ga_l = Al  + (size_t)(e0 + m) * En + colA;
            const u16* gb_h = Bth + zB + (size_t)(n0 + m) * En + colA;
            const u16* gb_l = Btl + zB + (size_t)(n0 + m) * En + colA;
            GLD_LDS16(ga_h, &AsH[id * 8]);
            GLD_LDS16(ga_l, &AsL[id * 8]);
            GLD_LDS16(gb_h, &BsH[id * 8]);
            GLD_LDS16(gb_l, &BsL[id * 8]);
        }
        __syncthreads();

        s8v aH[4], aL[4], bH[4], bL[4];
        #pragma unroll
        for (int i = 0; i < 4; ++i) {
            const int ai = ((m_off + 16 * i + r) * 4 + q) * 8;
            const int bi = ((n_off + 16 * i + r) * 4 + q) * 8;
            aH[i] = *(const s8v*)&AsH[ai];
            aL[i] = *(const s8v*)&AsL[ai];
            bH[i] = *(const s8v*)&BsH[bi];
            bL[i] = *(const s8v*)&BsL[bi];
        }
        #pragma unroll
        for (int i = 0; i < 4; ++i)
            #pragma unroll
            for (int j = 0; j < 4; ++j) {
                acc[i][j] = __builtin_amdgcn_mfma_f32_16x16x32_bf16(aH[i], bH[j], acc[i][j], 0, 0, 0);
                acc[i][j] = __builtin_amdgcn_mfma_f32_16x16x32_bf16(aH[i], bL[j], acc[i][j], 0, 0, 0);
                acc[i][j] = __builtin_amdgcn_mfma_f32_16x16x32_bf16(aL[i], bH[j], acc[i][j], 0, 0, 0);
            }
    }

    // C/D layout: col = lane&15 (= r), row = q*4 + reg
    #pragma unroll
    for (int i = 0; i < 4; ++i) {
        #pragma unroll
        for (int reg = 0; reg < 4; ++reg) {
            const int e = e0 + m_off + 16 * i + q * 4 + reg;
            const float bv = bias ? bias[e] : 0.0f;
            #pragma unroll
            for (int j = 0; j < 4; ++j) {
                const int w = n0 + n_off + 16 * j + r;
                Y[zY + (size_t)e * Wn + w] = acc[i][j][reg] + bv;
            }
        }
    }
}

// ---------------------------------------------------------------------------
// fp32 fallback GEMM (round-2 proven) — used if ws_size is too small.
// ---------------------------------------------------------------------------
__global__ __launch_bounds__(256, 2)
void gemm128(const float* __restrict__ L, const float* __restrict__ X,
             float* __restrict__ Y, const float* __restrict__ bias) {
    __shared__ float As[16][132];
    __shared__ float Bs[16][132];

    const int bz = blockIdx.z;
    const float* Xb = X + (size_t)bz * En * Wn;
    float*       Yb = Y + (size_t)bz * En * Wn;
    const int e0 = blockIdx.y * 128;
    const int w0 = blockIdx.x * 128;
    const int t  = threadIdx.x;
    const int tx = t & 15, ty = t >> 4;
    const int la_e = t >> 2, la_f = (t & 3) << 2;
    const int lb_f = t >> 5, lb_w = (t & 31) << 2;

    float acc[2][2][4][4] = {};

    for (int f0 = 0; f0 < En; f0 += 16) {
        f4 a0 = *(const f4*)&L [(size_t)(e0 + la_e)      * En + f0 + la_f];
        f4 a1 = *(const f4*)&L [(size_t)(e0 + la_e + 64) * En + f0 + la_f];
        f4 b0 = *(const f4*)&Xb[(size_t)(f0 + lb_f)      * Wn + w0 + lb_w];
        f4 b1 = *(const f4*)&Xb[(size_t)(f0 + lb_f + 8)  * Wn + w0 + lb_w];
        __syncthreads();
        As[la_f + 0][la_e] = a0[0]; As[la_f + 1][la_e] = a0[1];
        As[la_f + 2][la_e] = a0[2]; As[la_f + 3][la_e] = a0[3];
        As[la_f + 0][la_e + 64] = a1[0]; As[la_f + 1][la_e + 64] = a1[1];
        As[la_f + 2][la_e + 64] = a1[2]; As[la_f + 3][la_e + 64] = a1[3];
        *(f4*)&Bs[lb_f    ][lb_w] = b0;
        *(f4*)&Bs[lb_f + 8][lb_w] = b1;
        __syncthreads();
        #pragma unroll
        for (int kk = 0; kk < 16; ++kk) {
            f4 av0 = *(f4*)&As[kk][ty * 4];
            f4 av1 = *(f4*)&As[kk][ty * 4 + 64];
            f4 bv0 = *(f4*)&Bs[kk][tx * 4];
            f4 bv1 = *(f4*)&Bs[kk][tx * 4 + 64];
            #pragma unroll
            for (int i = 0; i < 4; ++i)
                #pragma unroll
                for (int j = 0; j < 4; ++j) {
                    acc[0][0][i][j] = fmaf(av0[i], bv0[j], acc[0][0][i][j]);
                    acc[0][1][i][j] = fmaf(av0[i], bv1[j], acc[0][1][i][j]);
                    acc[1][0][i][j] = fmaf(av1[i], bv0[j], acc[1][0][i][j]);
                    acc[1][1][i][j] = fmaf(av1[i], bv1[j], acc[1][1][i][j]);
                }
        }
    }

    #pragma unroll
    for (int eh = 0; eh < 2; ++eh)
        #pragma unroll
        for (int i = 0; i < 4; ++i) {
            const int e = e0 + eh * 64 + ty * 4 + i;
            const float bv = bias ? bias[e] : 0.0f;
            #pragma unroll
            for (int wh = 0; wh < 2; ++wh) {
                f4 v;
                #pragma unroll
                for (int j = 0; j < 4; ++j) v[j] = acc[eh][wh][i][j] + bv;
                *(f4*)&Yb[(size_t)e * Wn + w0 + wh * 64 + tx * 4] = v;
            }
        }
}

// ---------------------------------------------------------------------------
// Flash attention, softmax over q (query axis), causal mask q <= k. fp32.
// ---------------------------------------------------------------------------
__global__ __launch_bounds__(256, 2)
void attn64(const float* __restrict__ Qg, const float* __restrict__ Kg,
            const float* __restrict__ Vg, float* __restrict__ Og) {
    __shared__ float Ks[64][68];
    __shared__ float QP[64][68];
    __shared__ float Vt[64][68];
    __shared__ float mArr[64], lArr[64], alphaArr[64];
    __shared__ float red[4][64];

    const int kb = blockIdx.x, h = blockIdx.y, b = blockIdx.z;
    const size_t base = ((size_t)b * En + (size_t)h * DHn) * Wn;
    const float* Qp = Qg + base;
    const float* Kp = Kg + base;
    const float* Vp = Vg + base;
    float*       Op = Og + base;

    const int t  = threadIdx.x;
    const int tx = t & 15, ty = t >> 4;
    const int lr = t >> 4;
    const int lc = (t & 15) << 2;
    const int k0 = kb * 64;
    const int kc = t & 63, qg = t >> 6;

    #pragma unroll
    for (int r = 0; r < 4; ++r)
        *(f4*)&Ks[lr + r * 16][lc] =
            *(const f4*)&Kp[(size_t)(lr + r * 16) * Wn + k0 + lc];
    if (t < 64) { mArr[t] = -1e30f; lArr[t] = 0.0f; }
    float acc[4][4] = {};
    __syncthreads();

    for (int q0 = 0; q0 <= k0; q0 += 64) {
        #pragma unroll
        for (int r = 0; r < 4; ++r) {
            const int d = lr + r * 16;
            f4 qv = *(const f4*)&Qp[(size_t)d * Wn + q0 + lc];
            f4 vv = *(const f4*)&Vp[(size_t)d * Wn + q0 + lc];
            *(f4*)&QP[d][lc] = qv;
            Vt[lc + 0][d] = vv[0]; Vt[lc + 1][d] = vv[1];
            Vt[lc + 2][d] = vv[2]; Vt[lc + 3][d] = vv[3];
        }
        __syncthreads();

        float s[4][4] = {};
        #pragma unroll 4
        for (int d = 0; d < 64; ++d) {
            f4 kv = *(f4*)&Ks[d][tx * 4];
            f4 q2 = *(f4*)&QP[d][ty * 4];
            #pragma unroll
            for (int i = 0; i < 4; ++i)
                #pragma unroll
                for (int j = 0; j < 4; ++j)
                    s[i][j] = fmaf(q2[i], kv[j], s[i][j]);
        }
        if (q0 == k0) {
            #pragma unroll
            for (int i = 0; i < 4; ++i)
                #pragma unroll
                for (int j = 0; j < 4; ++j)
                    if (ty * 4 + i > tx * 4 + j) s[i][j] = -1e30f;
        }
        __syncthreads();
        #pragma unroll
        for (int i = 0; i < 4; ++i) {
            f4 v;
            #pragma unroll
            for (int j = 0; j < 4; ++j) v[j] = s[i][j];
            *(f4*)&QP[ty * 4 + i][tx * 4] = v;
        }
        __syncthreads();

        float sv[16];
        float lm = -1e30f;
        #pragma unroll
        for (int r = 0; r < 16; ++r) {
            sv[r] = QP[qg * 16 + r][kc];
            lm = fmaxf(lm, sv[r]);
        }
        red[qg][kc] = lm;
        __syncthreads();
        const float mt    = fmaxf(fmaxf(red[0][kc], red[1][kc]),
                                  fmaxf(red[2][kc], red[3][kc]));
        const float mprev = mArr[kc];
        const float mnew  = fmaxf(mprev, mt);
        float psum = 0.0f;
        #pragma unroll
        for (int r = 0; r < 16; ++r) {
            const float p = __expf(sv[r] - mnew);
            psum += p;
            QP[qg * 16 + r][kc] = p;
        }
        __syncthreads();
        red[qg][kc] = psum;
        __syncthreads();
        if (qg == 0) {
            const float alpha = __expf(mprev - mnew);
            lArr[kc] = lArr[kc] * alpha +
                       (red[0][kc] + red[1][kc] + red[2][kc] + red[3][kc]);
            mArr[kc]     = mnew;
            alphaArr[kc] = alpha;
        }
        __syncthreads();

        f4 al = *(f4*)&alphaArr[tx * 4];
        #pragma unroll
        for (int i = 0; i < 4; ++i)
            #pragma unroll
            for (int j = 0; j < 4; ++j)
                acc[i][j] *= al[j];
        #pragma unroll 4
        for (int q = 0; q < 64; ++q) {
            f4 pv = *(f4*)&QP[q][tx * 4];
            f4 v2 = *(f4*)&Vt[q][ty * 4];
            #pragma unroll
            for (int i = 0; i < 4; ++i)
                #pragma unroll
                for (int j = 0; j < 4; ++j)
                    acc[i][j] = fmaf(v2[i], pv[j], acc[i][j]);
        }
        __syncthreads();
    }

    f4 linv = *(f4*)&lArr[tx * 4];
    #pragma unroll
    for (int j = 0; j < 4; ++j) linv[j] = 1.0f / (linv[j] * 32.0f);
    #pragma unroll
    for (int i = 0; i < 4; ++i) {
        f4 v;
        #pragma unroll
        for (int j = 0; j < 4; ++j) v[j] = acc[i][j] * linv[j];
        *(f4*)&Op[(size_t)(ty * 4 + i) * Wn + k0 + tx * 4] = v;
    }
}

// ---------------------------------------------------------------------------
extern "C" void kernel_launch(void* const* d_in, const int* in_sizes, int n_in,
                              void* d_out, int out_size, void* d_ws, size_t ws_size,
                              hipStream_t stream) {
    const float* x    = (const float*)d_in[0];   // [3,B,E,W]: x[0]=K, x[1]=Q, x[2]=V
    const float* L_Q  = (const float*)d_in[1];
    const float* L_K  = (const float*)d_in[2];
    const float* L_V  = (const float*)d_in[3];
    const float* M    = (const float*)d_in[4];
    const float* bias = (const float*)d_in[5];
    float* out = (float*)d_out;

    const size_t mat   = (size_t)Bn * En * Wn;       // 8M floats
    const size_t matB  = mat * 4;                    // 33,554,432 bytes
    const size_t lmatB = (size_t)En * En * 2;        // 2 MB per bf16 L piece

    const size_t need_mfma = matB /*XtBuf hi+lo*/ + 8 * lmatB /*L splits*/
                           + 3 * matB /*Kp,Qp,Vp*/ + matB /*Ao*/;   // 184.5 MB

    if (ws_size >= need_mfma) {
        char* w = (char*)d_ws;
        u16*   XT_H = (u16*)(w);
        u16*   XT_L = (u16*)(w + matB / 2);
        u16*   Lsp  = (u16*)(w + matB);              // 8 pieces of lmatB
        float* Kp   = (float*)(w + matB + 8 * lmatB);
        float* Qp   = Kp + mat;
        float* Vp   = Qp + mat;
        float* Ao   = Vp + mat;

        u16* LKh = Lsp + 0 * (lmatB / 2); u16* LKl = Lsp + 1 * (lmatB / 2);
        u16* LQh = Lsp + 2 * (lmatB / 2); u16* LQl = Lsp + 3 * (lmatB / 2);
        u16* LVh = Lsp + 4 * (lmatB / 2); u16* LVl = Lsp + 5 * (lmatB / 2);
        u16* Mh  = Lsp + 6 * (lmatB / 2); u16* Ml  = Lsp + 7 * (lmatB / 2);

        const int n4L = En * En / 4;
        hipLaunchKernelGGL(split_plain, dim3(n4L / 256), dim3(256), 0, stream, L_K, LKh, LKl, n4L);
        hipLaunchKernelGGL(split_plain, dim3(n4L / 256), dim3(256), 0, stream, L_Q, LQh, LQl, n4L);
        hipLaunchKernelGGL(split_plain, dim3(n4L / 256), dim3(256), 0, stream, L_V, LVh, LVl, n4L);
        hipLaunchKernelGGL(split_plain, dim3(n4L / 256), dim3(256), 0, stream, M,   Mh,  Ml,  n4L);

        dim3 gt(Wn / 32, En / 32, Bn), bt(256);
        dim3 gg(Wn / 128, En / 128, Bn), bg(256);

        // K = L_K @ x[0]
        hipLaunchKernelGGL(split_t, gt, bt, 0, stream, x + 0 * mat, XT_H, XT_L);
        hipLaunchKernelGGL(gemm_mfma, gg, bg, 0, stream, LKh, LKl, XT_H, XT_L, Kp, (const float*)nullptr);
        // Q = L_Q @ x[1]
        hipLaunchKernelGGL(split_t, gt, bt, 0, stream, x + 1 * mat, XT_H, XT_L);
        hipLaunchKernelGGL(gemm_mfma, gg, bg, 0, stream, LQh, LQl, XT_H, XT_L, Qp, (const float*)nullptr);
        // V = L_V @ x[2]
        hipLaunchKernelGGL(split_t, gt, bt, 0, stream, x + 2 * mat, XT_H, XT_L);
        hipLaunchKernelGGL(gemm_mfma, gg, bg, 0, stream, LVh, LVl, XT_H, XT_L, Vp, (const float*)nullptr);

        dim3 ga(Wn / 64, Hn, Bn);
        hipLaunchKernelGGL(attn64, ga, dim3(256), 0, stream, Qp, Kp, Vp, Ao);

        // out = M @ Ao + b   (XtBuf reused for Ao split)
        hipLaunchKernelGGL(split_t, gt, bt, 0, stream, Ao, XT_H, XT_L);
        hipLaunchKernelGGL(gemm_mfma, gg, bg, 0, stream, Mh, Ml, XT_H, XT_L, out, bias);
    } else {
        // fallback: round-2 fp32 path (needs 4*matB = 134 MB)
        float* ws = (float*)d_ws;
        float* Kp = ws;
        float* Qp = ws + mat;
        float* Vp = ws + 2 * mat;
        float* Ao = ws + 3 * mat;

        dim3 gg(Wn / 128, En / 128, Bn), blk(256);
        hipLaunchKernelGGL(gemm128, gg, blk, 0, stream, L_K, x + 0 * mat, Kp, (const float*)nullptr);
        hipLaunchKernelGGL(gemm128, gg, blk, 0, stream, L_Q, x + 1 * mat, Qp, (const float*)nullptr);
        hipLaunchKernelGGL(gemm128, gg, blk, 0, stream, L_V, x + 2 * mat, Vp, (const float*)nullptr);

        dim3 ga(Wn / 64, Hn, Bn);
        hipLaunchKernelGGL(attn64, ga, blk, 0, stream, Qp, Kp, Vp, Ao);

        hipLaunchKernelGGL(gemm128, gg, blk, 0, stream, M, Ao, out, bias);
    }
}

// Round 4
// 772.610 us; speedup vs baseline: 1.9383x; 1.2108x over previous
//
#include <hip/hip_runtime.h>

typedef float  f4  __attribute__((ext_vector_type(4)));
typedef short  s8v __attribute__((ext_vector_type(8)));   // 8 bf16 (4 VGPRs)
typedef unsigned short u16;
typedef u16 us4 __attribute__((ext_vector_type(4)));

constexpr int En  = 1024;
constexpr int Wn  = 1024;
constexpr int Bn  = 8;
constexpr int Hn  = 16;
constexpr int DHn = 64;

__device__ inline u16 bf16rn(float x) {
    unsigned u = __float_as_uint(x);
    return (u16)((u + 0x7FFFu + ((u >> 16) & 1u)) >> 16);
}
__device__ inline float bf16tof(u16 h) { return __uint_as_float(((unsigned)h) << 16); }

#define GLD_LDS16(gp, lp) __builtin_amdgcn_global_load_lds(                      \
    (const __attribute__((address_space(1))) void*)(gp),                         \
    (__attribute__((address_space(3))) void*)(lp), 16, 0, 0)

// ---------------------------------------------------------------------------
// Elementwise split: fp32 -> bf16 hi/lo.
// ---------------------------------------------------------------------------
__global__ void split_plain(const float* __restrict__ in, u16* __restrict__ hi,
                            u16* __restrict__ lo, int n4) {
    int i = blockIdx.x * blockDim.x + threadIdx.x;
    if (i >= n4) return;
    f4 v = ((const f4*)in)[i];
    us4 h, l;
    #pragma unroll
    for (int k = 0; k < 4; ++k) {
        u16 hh = bf16rn(v[k]);
        h[k] = hh;
        l[k] = bf16rn(v[k] - bf16tof(hh));
    }
    ((us4*)hi)[i] = h;
    ((us4*)lo)[i] = l;
}

// ---------------------------------------------------------------------------
// Elementwise fp32 -> bf16 (hi only), for V.
// ---------------------------------------------------------------------------
__global__ void f32_to_bf16(const float* __restrict__ in, u16* __restrict__ out,
                            int n4) {
    int i = blockIdx.x * blockDim.x + threadIdx.x;
    if (i >= n4) return;
    f4 v = ((const f4*)in)[i];
    us4 o;
    #pragma unroll
    for (int k = 0; k < 4; ++k) o[k] = bf16rn(v[k]);
    ((us4*)out)[i] = o;
}

// ---------------------------------------------------------------------------
// Transpose + split: in [z][1024][1024] fp32 -> hi/lo [z][1024][1024] bf16,
// out[c][r] = in[r][c]. grid (32, 32, NB), block 256.
// ---------------------------------------------------------------------------
__global__ __launch_bounds__(256)
void split_t(const float* __restrict__ in, u16* __restrict__ hi,
             u16* __restrict__ lo) {
    __shared__ float T[32][33];
    const int z = blockIdx.z;
    const size_t zo = (size_t)z * En * Wn;
    const int r0 = blockIdx.y * 32, c0 = blockIdx.x * 32;
    const int t = threadIdx.x;
    const int row = t >> 3, c4 = (t & 7) << 2;

    f4 v = *(const f4*)&in[zo + (size_t)(r0 + row) * Wn + c0 + c4];
    T[row][c4 + 0] = v[0]; T[row][c4 + 1] = v[1];
    T[row][c4 + 2] = v[2]; T[row][c4 + 3] = v[3];
    __syncthreads();

    const int oc = row, r4 = c4;
    us4 h, l;
    #pragma unroll
    for (int i = 0; i < 4; ++i) {
        float x = T[r4 + i][oc];
        u16 hh = bf16rn(x);
        h[i] = hh;
        l[i] = bf16rn(x - bf16tof(hh));
    }
    *(us4*)&hi[zo + (size_t)(c0 + oc) * En + r0 + r4] = h;
    *(us4*)&lo[zo + (size_t)(c0 + oc) * En + r0 + r4] = l;
}

// ---------------------------------------------------------------------------
// Repack Q/K for attention: in fp32 [B,E,W] (e = h*64+d) ->
// out hi/lo bf16 [B*H][W][64] (w rows, d contiguous).
// grid (W/64, B*H), block 256.
// ---------------------------------------------------------------------------
__global__ __launch_bounds__(256)
void qk_repack(const float* __restrict__ in, u16* __restrict__ oh,
               u16* __restrict__ ol) {
    __shared__ float T[64][65];
    const int bh = blockIdx.y, w0 = blockIdx.x * 64;
    const int t = threadIdx.x;
    const int row = t >> 2, cc = (t & 3) << 4;   // row 0..63, 16-col chunk

    #pragma unroll
    for (int c = 0; c < 4; ++c) {
        f4 v = *(const f4*)&in[(size_t)(bh * 64 + row) * Wn + w0 + cc + c * 4];
        T[row][cc + c * 4 + 0] = v[0]; T[row][cc + c * 4 + 1] = v[1];
        T[row][cc + c * 4 + 2] = v[2]; T[row][cc + c * 4 + 3] = v[3];
    }
    __syncthreads();

    // write: out row w = row, d chunk = cc..cc+15
    const size_t ob = ((size_t)bh * Wn + w0 + row) * 64 + cc;
    #pragma unroll
    for (int c = 0; c < 4; ++c) {
        us4 h, l;
        #pragma unroll
        for (int j = 0; j < 4; ++j) {
            float x = T[cc + c * 4 + j][row];
            u16 hh = bf16rn(x);
            h[j] = hh;
            l[j] = bf16rn(x - bf16tof(hh));
        }
        *(us4*)&oh[ob + c * 4] = h;
        *(us4*)&ol[ob + c * 4] = l;
    }
}

// ---------------------------------------------------------------------------
// MFMA GEMM with bf16 hi/lo split operands (3-term: hh + hl + lh).
// ---------------------------------------------------------------------------
__global__ __launch_bounds__(256, 2)
void gemm_mfma(const u16* __restrict__ Ah,  const u16* __restrict__ Al,
               const u16* __restrict__ Bth, const u16* __restrict__ Btl,
               float* __restrict__ Y, const float* __restrict__ bias) {
    __shared__ u16 AsH[4096], AsL[4096], BsH[4096], BsL[4096];

    const int z  = blockIdx.z;
    const size_t zB = (size_t)z * Wn * En;
    const size_t zY = (size_t)z * En * Wn;
    const int e0 = blockIdx.y * 128, n0 = blockIdx.x * 128;
    const int t = threadIdx.x, lane = t & 63, wave = t >> 6;
    const int q = lane >> 4, r = lane & 15;
    const int m_off = (wave & 1) * 64, n_off = (wave >> 1) * 64;

    f4 acc[4][4];
    #pragma unroll
    for (int i = 0; i < 4; ++i)
        #pragma unroll
        for (int j = 0; j < 4; ++j) { acc[i][j][0]=0; acc[i][j][1]=0; acc[i][j][2]=0; acc[i][j][3]=0; }

    for (int kb = 0; kb < En; kb += 32) {
        __syncthreads();
        #pragma unroll
        for (int it = 0; it < 2; ++it) {
            const int id = t + 256 * it;
            const int m = id >> 2, g = id & 3;
            const size_t colA = (size_t)kb + 8 * g;
            const u16* ga_h = Ah  + (size_t)(e0 + m) * En + colA;
            const u16* ga_l = Al  + (size_t)(e0 + m) * En + colA;
            const u16* gb_h = Bth + zB + (size_t)(n0 + m) * En + colA;
            const u16* gb_l = Btl + zB + (size_t)(n0 + m) * En + colA;
            GLD_LDS16(ga_h, &AsH[id * 8]);
            GLD_LDS16(ga_l, &AsL[id * 8]);
            GLD_LDS16(gb_h, &BsH[id * 8]);
            GLD_LDS16(gb_l, &BsL[id * 8]);
        }
        __syncthreads();

        s8v aH[4], aL[4], bH[4], bL[4];
        #pragma unroll
        for (int i = 0; i < 4; ++i) {
            const int ai = ((m_off + 16 * i + r) * 4 + q) * 8;
            const int bi = ((n_off + 16 * i + r) * 4 + q) * 8;
            aH[i] = *(const s8v*)&AsH[ai];
            aL[i] = *(const s8v*)&AsL[ai];
            bH[i] = *(const s8v*)&BsH[bi];
            bL[i] = *(const s8v*)&BsL[bi];
        }
        #pragma unroll
        for (int i = 0; i < 4; ++i)
            #pragma unroll
            for (int j = 0; j < 4; ++j) {
                acc[i][j] = __builtin_amdgcn_mfma_f32_16x16x32_bf16(aH[i], bH[j], acc[i][j], 0, 0, 0);
                acc[i][j] = __builtin_amdgcn_mfma_f32_16x16x32_bf16(aH[i], bL[j], acc[i][j], 0, 0, 0);
                acc[i][j] = __builtin_amdgcn_mfma_f32_16x16x32_bf16(aL[i], bH[j], acc[i][j], 0, 0, 0);
            }
    }

    #pragma unroll
    for (int i = 0; i < 4; ++i) {
        #pragma unroll
        for (int reg = 0; reg < 4; ++reg) {
            const int e = e0 + m_off + 16 * i + q * 4 + reg;
            const float bv = bias ? bias[e] : 0.0f;
            #pragma unroll
            for (int j = 0; j < 4; ++j) {
                const int w = n0 + n_off + 16 * j + r;
                Y[zY + (size_t)e * Wn + w] = acc[i][j][reg] + bv;
            }
        }
    }
}

// ---------------------------------------------------------------------------
// MFMA flash attention (softmax over q, causal q <= k).
// QT/KT: bf16 hi/lo [B*H][W][64]; Vb: bf16 [B*H*64][W]; Ao: fp32 [B,E,W].
// grid (16, H, B), block 256 = 4 waves; wave owns 16 k-columns (k0+wave*16+r
// is the per-lane column). No __syncthreads in the q-loop; softmax state is
// per-lane (column) with quad-reductions via __shfl_xor 16/32.
// ---------------------------------------------------------------------------
__global__ __launch_bounds__(256, 2)
void attn_mfma(const u16* __restrict__ QTh, const u16* __restrict__ QTl,
               const u16* __restrict__ KTh, const u16* __restrict__ KTl,
               const u16* __restrict__ Vb,  float* __restrict__ Ao) {
    __shared__ u16 PT[4][16][72];                 // [wave][r(col)][q], pad 72

    const int kb = 15 - blockIdx.x;               // long blocks first
    const int h = blockIdx.y, b = blockIdx.z;
    const int bh = b * Hn + h;
    const int t = threadIdx.x, lane = t & 63, wave = t >> 6;
    const int r = lane & 15, quad = lane >> 4;
    const int k0 = kb * 64;
    const int kcol = k0 + wave * 16 + r;          // this lane's global column
    u16 (*pt)[72] = PT[wave];

    const size_t qkb = (size_t)bh * Wn * 64;      // [w][64] base
    const size_t vbb = (size_t)bh * 64 * Wn;      // [d][w] base

    // K fragments: once per block, live in registers.
    s8v kH[2], kL[2];
    #pragma unroll
    for (int s = 0; s < 2; ++s) {
        const size_t a = qkb + (size_t)kcol * 64 + s * 32 + quad * 8;
        kH[s] = *(const s8v*)&KTh[a];
        kL[s] = *(const s8v*)&KTl[a];
    }

    f4 o[4];                                      // O[d=16i+quad*4+reg][kcol]
    #pragma unroll
    for (int i = 0; i < 4; ++i) { o[i][0]=0; o[i][1]=0; o[i][2]=0; o[i][3]=0; }
    float m = -1e30f, l = 0.0f;

    for (int q0 = 0; q0 <= k0; q0 += 64) {
        // ---- S = Q^T K for this wave's 16 columns, 64 q rows (3-term split)
        f4 sacc[4];
        #pragma unroll
        for (int mt = 0; mt < 4; ++mt) { sacc[mt][0]=0; sacc[mt][1]=0; sacc[mt][2]=0; sacc[mt][3]=0; }
        #pragma unroll
        for (int s = 0; s < 2; ++s) {
            #pragma unroll
            for (int mt = 0; mt < 4; ++mt) {
                const size_t a = qkb + (size_t)(q0 + 16 * mt + r) * 64 + s * 32 + quad * 8;
                s8v qh = *(const s8v*)&QTh[a];
                s8v ql = *(const s8v*)&QTl[a];
                sacc[mt] = __builtin_amdgcn_mfma_f32_16x16x32_bf16(qh, kH[s], sacc[mt], 0, 0, 0);
                sacc[mt] = __builtin_amdgcn_mfma_f32_16x16x32_bf16(qh, kL[s], sacc[mt], 0, 0, 0);
                sacc[mt] = __builtin_amdgcn_mfma_f32_16x16x32_bf16(ql, kH[s], sacc[mt], 0, 0, 0);
            }
        }
        // ---- causal mask on the diagonal tile (q global > k global)
        if (q0 == k0) {
            const int klocal = wave * 16 + r;
            #pragma unroll
            for (int mt = 0; mt < 4; ++mt)
                #pragma unroll
                for (int reg = 0; reg < 4; ++reg)
                    if (16 * mt + quad * 4 + reg > klocal) sacc[mt][reg] = -1e30f;
        }
        // ---- online softmax over q (column = lane's r); quad reduction
        float tm = -1e30f;
        #pragma unroll
        for (int mt = 0; mt < 4; ++mt)
            #pragma unroll
            for (int reg = 0; reg < 4; ++reg) tm = fmaxf(tm, sacc[mt][reg]);
        tm = fmaxf(tm, __shfl_xor(tm, 16));
        tm = fmaxf(tm, __shfl_xor(tm, 32));
        const float mnew  = fmaxf(m, tm);
        const float alpha = __expf(m - mnew);
        float ps = 0.0f;
        #pragma unroll
        for (int mt = 0; mt < 4; ++mt) {
            us4 pk;
            #pragma unroll
            for (int reg = 0; reg < 4; ++reg) {
                float p = __expf(sacc[mt][reg] - mnew);
                ps += p;
                pk[reg] = bf16rn(p);
            }
            *(us4*)&pt[r][16 * mt + quad * 4] = pk;   // P^T[col r][q]
        }
        ps += __shfl_xor(ps, 16);
        ps += __shfl_xor(ps, 32);
        l = l * alpha + ps;
        m = mnew;
        #pragma unroll
        for (int i = 0; i < 4; ++i) {
            o[i][0] *= alpha; o[i][1] *= alpha; o[i][2] *= alpha; o[i][3] *= alpha;
        }
        // ---- O += V P  (V A-frags direct from global, P B-frags from LDS)
        #pragma unroll
        for (int s = 0; s < 2; ++s) {
            s8v pf = *(const s8v*)&pt[r][s * 32 + quad * 8];
            #pragma unroll
            for (int i = 0; i < 4; ++i) {
                const size_t va = vbb + (size_t)(16 * i + r) * Wn + q0 + s * 32 + quad * 8;
                s8v vf = *(const s8v*)&Vb[va];
                o[i] = __builtin_amdgcn_mfma_f32_16x16x32_bf16(vf, pf, o[i], 0, 0, 0);
            }
        }
    }

    const float inv = 1.0f / (l * 32.0f);
    #pragma unroll
    for (int i = 0; i < 4; ++i)
        #pragma unroll
        for (int reg = 0; reg < 4; ++reg)
            Ao[(size_t)(bh * 64 + 16 * i + quad * 4 + reg) * Wn + kcol] = o[i][reg] * inv;
}

// ---------------------------------------------------------------------------
// fp32 fallback GEMM + attention (round-2 proven).
// ---------------------------------------------------------------------------
__global__ __launch_bounds__(256, 2)
void gemm128(const float* __restrict__ L, const float* __restrict__ X,
             float* __restrict__ Y, const float* __restrict__ bias) {
    __shared__ float As[16][132];
    __shared__ float Bs[16][132];

    const int bz = blockIdx.z;
    const float* Xb = X + (size_t)bz * En * Wn;
    float*       Yb = Y + (size_t)bz * En * Wn;
    const int e0 = blockIdx.y * 128;
    const int w0 = blockIdx.x * 128;
    const int t  = threadIdx.x;
    const int tx = t & 15, ty = t >> 4;
    const int la_e = t >> 2, la_f = (t & 3) << 2;
    const int lb_f = t >> 5, lb_w = (t & 31) << 2;

    float acc[2][2][4][4] = {};

    for (int f0 = 0; f0 < En; f0 += 16) {
        f4 a0 = *(const f4*)&L [(size_t)(e0 + la_e)      * En + f0 + la_f];
        f4 a1 = *(const f4*)&L [(size_t)(e0 + la_e + 64) * En + f0 + la_f];
        f4 b0 = *(const f4*)&Xb[(size_t)(f0 + lb_f)      * Wn + w0 + lb_w];
        f4 b1 = *(const f4*)&Xb[(size_t)(f0 + lb_f + 8)  * Wn + w0 + lb_w];
        __syncthreads();
        As[la_f + 0][la_e] = a0[0]; As[la_f + 1][la_e] = a0[1];
        As[la_f + 2][la_e] = a0[2]; As[la_f + 3][la_e] = a0[3];
        As[la_f + 0][la_e + 64] = a1[0]; As[la_f + 1][la_e + 64] = a1[1];
        As[la_f + 2][la_e + 64] = a1[2]; As[la_f + 3][la_e + 64] = a1[3];
        *(f4*)&Bs[lb_f    ][lb_w] = b0;
        *(f4*)&Bs[lb_f + 8][lb_w] = b1;
        __syncthreads();
        #pragma unroll
        for (int kk = 0; kk < 16; ++kk) {
            f4 av0 = *(f4*)&As[kk][ty * 4];
            f4 av1 = *(f4*)&As[kk][ty * 4 + 64];
            f4 bv0 = *(f4*)&Bs[kk][tx * 4];
            f4 bv1 = *(f4*)&Bs[kk][tx * 4 + 64];
            #pragma unroll
            for (int i = 0; i < 4; ++i)
                #pragma unroll
                for (int j = 0; j < 4; ++j) {
                    acc[0][0][i][j] = fmaf(av0[i], bv0[j], acc[0][0][i][j]);
                    acc[0][1][i][j] = fmaf(av0[i], bv1[j], acc[0][1][i][j]);
                    acc[1][0][i][j] = fmaf(av1[i], bv0[j], acc[1][0][i][j]);
                    acc[1][1][i][j] = fmaf(av1[i], bv1[j], acc[1][1][i][j]);
                }
        }
    }

    #pragma unroll
    for (int eh = 0; eh < 2; ++eh)
        #pragma unroll
        for (int i = 0; i < 4; ++i) {
            const int e = e0 + eh * 64 + ty * 4 + i;
            const float bv = bias ? bias[e] : 0.0f;
            #pragma unroll
            for (int wh = 0; wh < 2; ++wh) {
                f4 v;
                #pragma unroll
                for (int j = 0; j < 4; ++j) v[j] = acc[eh][wh][i][j] + bv;
                *(f4*)&Yb[(size_t)e * Wn + w0 + wh * 64 + tx * 4] = v;
            }
        }
}

__global__ __launch_bounds__(256, 2)
void attn64(const float* __restrict__ Qg, const float* __restrict__ Kg,
            const float* __restrict__ Vg, float* __restrict__ Og) {
    __shared__ float Ks[64][68];
    __shared__ float QP[64][68];
    __shared__ float Vt[64][68];
    __shared__ float mArr[64], lArr[64], alphaArr[64];
    __shared__ float red[4][64];

    const int kb = blockIdx.x, h = blockIdx.y, b = blockIdx.z;
    const size_t base = ((size_t)b * En + (size_t)h * DHn) * Wn;
    const float* Qp = Qg + base;
    const float* Kp = Kg + base;
    const float* Vp = Vg + base;
    float*       Op = Og + base;

    const int t  = threadIdx.x;
    const int tx = t & 15, ty = t >> 4;
    const int lr = t >> 4;
    const int lc = (t & 15) << 2;
    const int k0 = kb * 64;
    const int kc = t & 63, qg = t >> 6;

    #pragma unroll
    for (int r = 0; r < 4; ++r)
        *(f4*)&Ks[lr + r * 16][lc] =
            *(const f4*)&Kp[(size_t)(lr + r * 16) * Wn + k0 + lc];
    if (t < 64) { mArr[t] = -1e30f; lArr[t] = 0.0f; }
    float acc[4][4] = {};
    __syncthreads();

    for (int q0 = 0; q0 <= k0; q0 += 64) {
        #pragma unroll
        for (int r = 0; r < 4; ++r) {
            const int d = lr + r * 16;
            f4 qv = *(const f4*)&Qp[(size_t)d * Wn + q0 + lc];
            f4 vv = *(const f4*)&Vp[(size_t)d * Wn + q0 + lc];
            *(f4*)&QP[d][lc] = qv;
            Vt[lc + 0][d] = vv[0]; Vt[lc + 1][d] = vv[1];
            Vt[lc + 2][d] = vv[2]; Vt[lc + 3][d] = vv[3];
        }
        __syncthreads();

        float s[4][4] = {};
        #pragma unroll 4
        for (int d = 0; d < 64; ++d) {
            f4 kv = *(f4*)&Ks[d][tx * 4];
            f4 q2 = *(f4*)&QP[d][ty * 4];
            #pragma unroll
            for (int i = 0; i < 4; ++i)
                #pragma unroll
                for (int j = 0; j < 4; ++j)
                    s[i][j] = fmaf(q2[i], kv[j], s[i][j]);
        }
        if (q0 == k0) {
            #pragma unroll
            for (int i = 0; i < 4; ++i)
                #pragma unroll
                for (int j = 0; j < 4; ++j)
                    if (ty * 4 + i > tx * 4 + j) s[i][j] = -1e30f;
        }
        __syncthreads();
        #pragma unroll
        for (int i = 0; i < 4; ++i) {
            f4 v;
            #pragma unroll
            for (int j = 0; j < 4; ++j) v[j] = s[i][j];
            *(f4*)&QP[ty * 4 + i][tx * 4] = v;
        }
        __syncthreads();

        float sv[16];
        float lm = -1e30f;
        #pragma unroll
        for (int r = 0; r < 16; ++r) {
            sv[r] = QP[qg * 16 + r][kc];
            lm = fmaxf(lm, sv[r]);
        }
        red[qg][kc] = lm;
        __syncthreads();
        const float mt    = fmaxf(fmaxf(red[0][kc], red[1][kc]),
                                  fmaxf(red[2][kc], red[3][kc]));
        const float mprev = mArr[kc];
        const float mnew  = fmaxf(mprev, mt);
        float psum = 0.0f;
        #pragma unroll
        for (int r = 0; r < 16; ++r) {
            const float p = __expf(sv[r] - mnew);
            psum += p;
            QP[qg * 16 + r][kc] = p;
        }
        __syncthreads();
        red[qg][kc] = psum;
        __syncthreads();
        if (qg == 0) {
            const float alpha = __expf(mprev - mnew);
            lArr[kc] = lArr[kc] * alpha +
                       (red[0][kc] + red[1][kc] + red[2][kc] + red[3][kc]);
            mArr[kc]     = mnew;
            alphaArr[kc] = alpha;
        }
        __syncthreads();

        f4 al = *(f4*)&alphaArr[tx * 4];
        #pragma unroll
        for (int i = 0; i < 4; ++i)
            #pragma unroll
            for (int j = 0; j < 4; ++j)
                acc[i][j] *= al[j];
        #pragma unroll 4
        for (int q = 0; q < 64; ++q) {
            f4 pv = *(f4*)&QP[q][tx * 4];
            f4 v2 = *(f4*)&Vt[q][ty * 4];
            #pragma unroll
            for (int i = 0; i < 4; ++i)
                #pragma unroll
                for (int j = 0; j < 4; ++j)
                    acc[i][j] = fmaf(v2[i], pv[j], acc[i][j]);
        }
        __syncthreads();
    }

    f4 linv = *(f4*)&lArr[tx * 4];
    #pragma unroll
    for (int j = 0; j < 4; ++j) linv[j] = 1.0f / (linv[j] * 32.0f);
    #pragma unroll
    for (int i = 0; i < 4; ++i) {
        f4 v;
        #pragma unroll
        for (int j = 0; j < 4; ++j) v[j] = acc[i][j] * linv[j];
        *(f4*)&Op[(size_t)(ty * 4 + i) * Wn + k0 + tx * 4] = v;
    }
}

// ---------------------------------------------------------------------------
extern "C" void kernel_launch(void* const* d_in, const int* in_sizes, int n_in,
                              void* d_out, int out_size, void* d_ws, size_t ws_size,
                              hipStream_t stream) {
    const float* x    = (const float*)d_in[0];   // [3,B,E,W]: x[0]=K, x[1]=Q, x[2]=V
    const float* L_Q  = (const float*)d_in[1];
    const float* L_K  = (const float*)d_in[2];
    const float* L_V  = (const float*)d_in[3];
    const float* M    = (const float*)d_in[4];
    const float* bias = (const float*)d_in[5];
    float* out = (float*)d_out;

    const size_t mat   = (size_t)Bn * En * Wn;       // 8M elements
    const size_t matB  = mat * 4;                    // 33,554,432 bytes
    const size_t lmatB = (size_t)En * En * 2;        // 2 MB per bf16 L piece
    const size_t need  = 8 * lmatB + 5 * matB;       // 184,549,376 B (proven fit)

    if (ws_size >= need) {
        char* w = (char*)d_ws;
        u16*  Lsp = (u16*)w;                         // 16 MB, 8 pieces
        char* XT  = w + 8 * lmatB;                   // x^T splits, later Ao^T
        char* RC  = XT + matB;                       // Kp fp32 -> QT hi/lo
        char* RD  = RC + matB;                       // Qp fp32 -> Vb bf16
        char* RE  = RD + matB;                       // Vp fp32 -> Ao fp32
        char* RF  = RE + matB;                       // KT hi/lo

        u16* LKh = Lsp + 0 * (lmatB / 2); u16* LKl = Lsp + 1 * (lmatB / 2);
        u16* LQh = Lsp + 2 * (lmatB / 2); u16* LQl = Lsp + 3 * (lmatB / 2);
        u16* LVh = Lsp + 4 * (lmatB / 2); u16* LVl = Lsp + 5 * (lmatB / 2);
        u16* Mh  = Lsp + 6 * (lmatB / 2); u16* Ml  = Lsp + 7 * (lmatB / 2);

        u16* XT_H = (u16*)XT;          u16* XT_L = (u16*)(XT + matB / 2);
        float* Kp = (float*)RC;
        u16* KT_h = (u16*)RF;          u16* KT_l = (u16*)(RF + matB / 2);
        float* Qp = (float*)RD;
        u16* QT_h = (u16*)RC;          u16* QT_l = (u16*)(RC + matB / 2);
        float* Vp = (float*)RE;
        u16* Vb   = (u16*)RD;
        float* Ao = (float*)RE;

        const int n4L = En * En / 4;
        hipLaunchKernelGGL(split_plain, dim3(n4L / 256), dim3(256), 0, stream, L_K, LKh, LKl, n4L);
        hipLaunchKernelGGL(split_plain, dim3(n4L / 256), dim3(256), 0, stream, L_Q, LQh, LQl, n4L);
        hipLaunchKernelGGL(split_plain, dim3(n4L / 256), dim3(256), 0, stream, L_V, LVh, LVl, n4L);
        hipLaunchKernelGGL(split_plain, dim3(n4L / 256), dim3(256), 0, stream, M,   Mh,  Ml,  n4L);

        dim3 gt(Wn / 32, En / 32, Bn), bt(256);
        dim3 gg(Wn / 128, En / 128, Bn), bg(256);
        dim3 gr(Wn / 64, Bn * Hn);

        // K = L_K @ x[0]; repack -> KT
        hipLaunchKernelGGL(split_t, gt, bt, 0, stream, x + 0 * mat, XT_H, XT_L);
        hipLaunchKernelGGL(gemm_mfma, gg, bg, 0, stream, LKh, LKl, XT_H, XT_L, Kp, (const float*)nullptr);
        hipLaunchKernelGGL(qk_repack, gr, dim3(256), 0, stream, Kp, KT_h, KT_l);
        // Q = L_Q @ x[1]; repack -> QT (into Kp region)
        hipLaunchKernelGGL(split_t, gt, bt, 0, stream, x + 1 * mat, XT_H, XT_L);
        hipLaunchKernelGGL(gemm_mfma, gg, bg, 0, stream, LQh, LQl, XT_H, XT_L, Qp, (const float*)nullptr);
        hipLaunchKernelGGL(qk_repack, gr, dim3(256), 0, stream, Qp, QT_h, QT_l);
        // V = L_V @ x[2]; cast -> Vb (into Qp region)
        hipLaunchKernelGGL(split_t, gt, bt, 0, stream, x + 2 * mat, XT_H, XT_L);
        hipLaunchKernelGGL(gemm_mfma, gg, bg, 0, stream, LVh, LVl, XT_H, XT_L, Vp, (const float*)nullptr);
        hipLaunchKernelGGL(f32_to_bf16, dim3((int)(mat / 4 / 256)), dim3(256), 0, stream, Vp, Vb, (int)(mat / 4));

        // attention -> Ao (into Vp region)
        dim3 ga(Wn / 64, Hn, Bn);
        hipLaunchKernelGGL(attn_mfma, ga, dim3(256), 0, stream, QT_h, QT_l, KT_h, KT_l, Vb, Ao);

        // out = M @ Ao + b
        hipLaunchKernelGGL(split_t, gt, bt, 0, stream, Ao, XT_H, XT_L);
        hipLaunchKernelGGL(gemm_mfma, gg, bg, 0, stream, Mh, Ml, XT_H, XT_L, out, bias);
    } else {
        // fallback: fp32 path (needs 4*matB = 134 MB)
        float* ws = (float*)d_ws;
        float* Kp = ws;
        float* Qp = ws + mat;
        float* Vp = ws + 2 * mat;
        float* Ao = ws + 3 * mat;

        dim3 gg(Wn / 128, En / 128, Bn), blk(256);
        hipLaunchKernelGGL(gemm128, gg, blk, 0, stream, L_K, x + 0 * mat, Kp, (const float*)nullptr);
        hipLaunchKernelGGL(gemm128, gg, blk, 0, stream, L_Q, x + 1 * mat, Qp, (const float*)nullptr);
        hipLaunchKernelGGL(gemm128, gg, blk, 0, stream, L_V, x + 2 * mat, Vp, (const float*)nullptr);

        dim3 ga(Wn / 64, Hn, Bn);
        hipLaunchKernelGGL(attn64, ga, blk, 0, stream, Qp, Kp, Vp, Ao);

        hipLaunchKernelGGL(gemm128, gg, blk, 0, stream, M, Ao, out, bias);
    }
}

// Round 5
// 544.176 us; speedup vs baseline: 2.7520x; 1.4198x over previous
//
#include <hip/hip_runtime.h>

typedef float  f4  __attribute__((ext_vector_type(4)));
typedef short  s8v __attribute__((ext_vector_type(8)));   // 8 bf16 (4 VGPRs)
typedef unsigned short u16;
typedef u16 us4 __attribute__((ext_vector_type(4)));

constexpr int En  = 1024;
constexpr int Wn  = 1024;
constexpr int Bn  = 8;
constexpr int Hn  = 16;
constexpr int DHn = 64;

__device__ inline u16 bf16rn(float x) {
    unsigned u = __float_as_uint(x);
    return (u16)((u + 0x7FFFu + ((u >> 16) & 1u)) >> 16);
}
__device__ inline float bf16tof(u16 h) { return __uint_as_float(((unsigned)h) << 16); }

#define GLD_LDS16(gp, lp) __builtin_amdgcn_global_load_lds(                      \
    (const __attribute__((address_space(1))) void*)(gp),                         \
    (__attribute__((address_space(3))) void*)(lp), 16, 0, 0)

// ---------------------------------------------------------------------------
// Elementwise split: fp32 -> bf16 hi/lo.
// ---------------------------------------------------------------------------
__global__ void split_plain(const float* __restrict__ in, u16* __restrict__ hi,
                            u16* __restrict__ lo, int n4) {
    int i = blockIdx.x * blockDim.x + threadIdx.x;
    if (i >= n4) return;
    f4 v = ((const f4*)in)[i];
    us4 h, l;
    #pragma unroll
    for (int k = 0; k < 4; ++k) {
        u16 hh = bf16rn(v[k]);
        h[k] = hh;
        l[k] = bf16rn(v[k] - bf16tof(hh));
    }
    ((us4*)hi)[i] = h;
    ((us4*)lo)[i] = l;
}

// ---------------------------------------------------------------------------
// Elementwise fp32 -> bf16 (hi only), for V.
// ---------------------------------------------------------------------------
__global__ void f32_to_bf16(const float* __restrict__ in, u16* __restrict__ out,
                            int n4) {
    int i = blockIdx.x * blockDim.x + threadIdx.x;
    if (i >= n4) return;
    f4 v = ((const f4*)in)[i];
    us4 o;
    #pragma unroll
    for (int k = 0; k < 4; ++k) o[k] = bf16rn(v[k]);
    ((us4*)out)[i] = o;
}

// ---------------------------------------------------------------------------
// Transpose + split: in [z][1024][1024] fp32 -> hi/lo [z][1024][1024] bf16.
// ---------------------------------------------------------------------------
__global__ __launch_bounds__(256)
void split_t(const float* __restrict__ in, u16* __restrict__ hi,
             u16* __restrict__ lo) {
    __shared__ float T[32][33];
    const int z = blockIdx.z;
    const size_t zo = (size_t)z * En * Wn;
    const int r0 = blockIdx.y * 32, c0 = blockIdx.x * 32;
    const int t = threadIdx.x;
    const int row = t >> 3, c4 = (t & 7) << 2;

    f4 v = *(const f4*)&in[zo + (size_t)(r0 + row) * Wn + c0 + c4];
    T[row][c4 + 0] = v[0]; T[row][c4 + 1] = v[1];
    T[row][c4 + 2] = v[2]; T[row][c4 + 3] = v[3];
    __syncthreads();

    const int oc = row, r4 = c4;
    us4 h, l;
    #pragma unroll
    for (int i = 0; i < 4; ++i) {
        float x = T[r4 + i][oc];
        u16 hh = bf16rn(x);
        h[i] = hh;
        l[i] = bf16rn(x - bf16tof(hh));
    }
    *(us4*)&hi[zo + (size_t)(c0 + oc) * En + r0 + r4] = h;
    *(us4*)&lo[zo + (size_t)(c0 + oc) * En + r0 + r4] = l;
}

// ---------------------------------------------------------------------------
// Repack Q/K for attention: fp32 [B,E,W] -> hi/lo bf16 [B*H][W][64].
// ---------------------------------------------------------------------------
__global__ __launch_bounds__(256)
void qk_repack(const float* __restrict__ in, u16* __restrict__ oh,
               u16* __restrict__ ol) {
    __shared__ float T[64][65];
    const int bh = blockIdx.y, w0 = blockIdx.x * 64;
    const int t = threadIdx.x;
    const int row = t >> 2, cc = (t & 3) << 4;

    #pragma unroll
    for (int c = 0; c < 4; ++c) {
        f4 v = *(const f4*)&in[(size_t)(bh * 64 + row) * Wn + w0 + cc + c * 4];
        T[row][cc + c * 4 + 0] = v[0]; T[row][cc + c * 4 + 1] = v[1];
        T[row][cc + c * 4 + 2] = v[2]; T[row][cc + c * 4 + 3] = v[3];
    }
    __syncthreads();

    const size_t ob = ((size_t)bh * Wn + w0 + row) * 64 + cc;
    #pragma unroll
    for (int c = 0; c < 4; ++c) {
        us4 h, l;
        #pragma unroll
        for (int j = 0; j < 4; ++j) {
            float x = T[cc + c * 4 + j][row];
            u16 hh = bf16rn(x);
            h[j] = hh;
            l[j] = bf16rn(x - bf16tof(hh));
        }
        *(us4*)&oh[ob + c * 4] = h;
        *(us4*)&ol[ob + c * 4] = l;
    }
}

// ---------------------------------------------------------------------------
// MFMA GEMM with bf16 hi/lo split operands (3-term: hh + hl + lh).
// ---------------------------------------------------------------------------
__global__ __launch_bounds__(256, 2)
void gemm_mfma(const u16* __restrict__ Ah,  const u16* __restrict__ Al,
               const u16* __restrict__ Bth, const u16* __restrict__ Btl,
               float* __restrict__ Y, const float* __restrict__ bias) {
    __shared__ u16 AsH[4096], AsL[4096], BsH[4096], BsL[4096];

    const int z  = blockIdx.z;
    const size_t zB = (size_t)z * Wn * En;
    const size_t zY = (size_t)z * En * Wn;
    const int e0 = blockIdx.y * 128, n0 = blockIdx.x * 128;
    const int t = threadIdx.x, lane = t & 63, wave = t >> 6;
    const int q = lane >> 4, r = lane & 15;
    const int m_off = (wave & 1) * 64, n_off = (wave >> 1) * 64;

    f4 acc[4][4];
    #pragma unroll
    for (int i = 0; i < 4; ++i)
        #pragma unroll
        for (int j = 0; j < 4; ++j) { acc[i][j][0]=0; acc[i][j][1]=0; acc[i][j][2]=0; acc[i][j][3]=0; }

    for (int kb = 0; kb < En; kb += 32) {
        __syncthreads();
        #pragma unroll
        for (int it = 0; it < 2; ++it) {
            const int id = t + 256 * it;
            const int m = id >> 2, g = id & 3;
            const size_t colA = (size_t)kb + 8 * g;
            const u16* ga_h = Ah  + (size_t)(e0 + m) * En + colA;
            const u16* ga_l = Al  + (size_t)(e0 + m) * En + colA;
            const u16* gb_h = Bth + zB + (size_t)(n0 + m) * En + colA;
            const u16* gb_l = Btl + zB + (size_t)(n0 + m) * En + colA;
            GLD_LDS16(ga_h, &AsH[id * 8]);
            GLD_LDS16(ga_l, &AsL[id * 8]);
            GLD_LDS16(gb_h, &BsH[id * 8]);
            GLD_LDS16(gb_l, &BsL[id * 8]);
        }
        __syncthreads();

        s8v aH[4], aL[4], bH[4], bL[4];
        #pragma unroll
        for (int i = 0; i < 4; ++i) {
            const int ai = ((m_off + 16 * i + r) * 4 + q) * 8;
            const int bi = ((n_off + 16 * i + r) * 4 + q) * 8;
            aH[i] = *(const s8v*)&AsH[ai];
            aL[i] = *(const s8v*)&AsL[ai];
            bH[i] = *(const s8v*)&BsH[bi];
            bL[i] = *(const s8v*)&BsL[bi];
        }
        #pragma unroll
        for (int i = 0; i < 4; ++i)
            #pragma unroll
            for (int j = 0; j < 4; ++j) {
                acc[i][j] = __builtin_amdgcn_mfma_f32_16x16x32_bf16(aH[i], bH[j], acc[i][j], 0, 0, 0);
                acc[i][j] = __builtin_amdgcn_mfma_f32_16x16x32_bf16(aH[i], bL[j], acc[i][j], 0, 0, 0);
                acc[i][j] = __builtin_amdgcn_mfma_f32_16x16x32_bf16(aL[i], bH[j], acc[i][j], 0, 0, 0);
            }
    }

    #pragma unroll
    for (int i = 0; i < 4; ++i) {
        #pragma unroll
        for (int reg = 0; reg < 4; ++reg) {
            const int e = e0 + m_off + 16 * i + q * 4 + reg;
            const float bv = bias ? bias[e] : 0.0f;
            #pragma unroll
            for (int j = 0; j < 4; ++j) {
                const int w = n0 + n_off + 16 * j + r;
                Y[zY + (size_t)e * Wn + w] = acc[i][j][reg] + bv;
            }
        }
    }
}

// ---------------------------------------------------------------------------
// MFMA flash attention v2: LDS-staged (global_load_lds, double-buffered),
// XCD-swizzled 1-D grid (all kb blocks of one bh -> same XCD).
// QT/KT: bf16 hi/lo [B*H][W][64]; Vb: bf16 [B*H][64][W]; Ao: fp32 [B,E,W].
// 2048 blocks, 256 thr = 4 waves; wave owns 16 k-columns. One barrier/iter;
// prefetch of tile q0+64 issued right after it, in flight during compute.
// ---------------------------------------------------------------------------
__global__ __launch_bounds__(256, 2)
void attn_mfma2(const u16* __restrict__ QTh, const u16* __restrict__ QTl,
                const u16* __restrict__ KTh, const u16* __restrict__ KTl,
                const u16* __restrict__ Vb,  float* __restrict__ Ao) {
    __shared__ u16 QsH[2][4096], QsL[2][4096], Vs[2][4096];   // [q][d] chunks
    __shared__ u16 PT[4][16][72];                             // per-wave P^T

    const int id   = blockIdx.x;
    const int rest = id >> 3;
    const int kb   = 15 - (rest & 15);              // long blocks first
    const int bh   = (id & 7) + 8 * (rest >> 4);    // id%8 fixed per bh -> XCD

    const int t = threadIdx.x, lane = t & 63, wave = t >> 6;
    const int r = lane & 15, quad = lane >> 4;
    const int k0 = kb * 64;
    const int kcol = k0 + wave * 16 + r;
    u16 (*pt)[72] = PT[wave];

    const size_t qkb = (size_t)bh * Wn * 64;        // [w][64]
    const size_t vbb = (size_t)bh * 64 * Wn;        // [d][w]

    // K fragments: once per block, in registers.
    s8v kH[2], kL[2];
    #pragma unroll
    for (int s = 0; s < 2; ++s) {
        const size_t a = qkb + (size_t)kcol * 64 + s * 32 + quad * 8;
        kH[s] = *(const s8v*)&KTh[a];
        kL[s] = *(const s8v*)&KTl[a];
    }

    f4 o[4];
    #pragma unroll
    for (int i = 0; i < 4; ++i) { o[i][0]=0; o[i][1]=0; o[i][2]=0; o[i][3]=0; }
    float m = -1e30f, l = 0.0f;

    // ---- stage tile q0 into LDS buffer `buf` (6 GLD x 16B per thread)
    auto stage = [&](int q0, int buf) {
        const size_t g = qkb + (size_t)q0 * 64;
        #pragma unroll
        for (int it = 0; it < 2; ++it) {
            const int c = t + it * 256;             // chunk 0..511 (16B each)
            GLD_LDS16(QTh + g + c * 8, &QsH[buf][c * 8]);
            GLD_LDS16(QTl + g + c * 8, &QsL[buf][c * 8]);
            GLD_LDS16(Vb + vbb + (size_t)(c >> 3) * Wn + q0 + (c & 7) * 8,
                      &Vs[buf][c * 8]);
        }
    };

    stage(0, 0);
    int buf = 0;

    for (int q0 = 0; q0 <= k0; q0 += 64) {
        __syncthreads();                            // drains stage(buf); guards buf reuse
        if (q0 + 64 <= k0) stage(q0 + 64, buf ^ 1); // prefetch, overlaps compute

        // ---- S = Q^T K (3-term hi/lo split), frags from LDS
        f4 sacc[4];
        #pragma unroll
        for (int mt = 0; mt < 4; ++mt) { sacc[mt][0]=0; sacc[mt][1]=0; sacc[mt][2]=0; sacc[mt][3]=0; }
        #pragma unroll
        for (int s = 0; s < 2; ++s) {
            #pragma unroll
            for (int mt = 0; mt < 4; ++mt) {
                const int a = (16 * mt + r) * 64 + s * 32 + quad * 8;
                s8v qh = *(const s8v*)&QsH[buf][a];
                s8v ql = *(const s8v*)&QsL[buf][a];
                sacc[mt] = __builtin_amdgcn_mfma_f32_16x16x32_bf16(qh, kH[s], sacc[mt], 0, 0, 0);
                sacc[mt] = __builtin_amdgcn_mfma_f32_16x16x32_bf16(qh, kL[s], sacc[mt], 0, 0, 0);
                sacc[mt] = __builtin_amdgcn_mfma_f32_16x16x32_bf16(ql, kH[s], sacc[mt], 0, 0, 0);
            }
        }
        // ---- causal mask on the diagonal tile
        if (q0 == k0) {
            const int klocal = wave * 16 + r;
            #pragma unroll
            for (int mt = 0; mt < 4; ++mt)
                #pragma unroll
                for (int reg = 0; reg < 4; ++reg)
                    if (16 * mt + quad * 4 + reg > klocal) sacc[mt][reg] = -1e30f;
        }
        // ---- online softmax over q (per-lane column), quad reduce via shfl
        float tm = -1e30f;
        #pragma unroll
        for (int mt = 0; mt < 4; ++mt)
            #pragma unroll
            for (int reg = 0; reg < 4; ++reg) tm = fmaxf(tm, sacc[mt][reg]);
        tm = fmaxf(tm, __shfl_xor(tm, 16));
        tm = fmaxf(tm, __shfl_xor(tm, 32));
        const float mnew  = fmaxf(m, tm);
        const float alpha = __expf(m - mnew);
        float ps = 0.0f;
        #pragma unroll
        for (int mt = 0; mt < 4; ++mt) {
            us4 pk;
            #pragma unroll
            for (int reg = 0; reg < 4; ++reg) {
                float p = __expf(sacc[mt][reg] - mnew);
                ps += p;
                pk[reg] = bf16rn(p);
            }
            *(us4*)&pt[r][16 * mt + quad * 4] = pk;
        }
        ps += __shfl_xor(ps, 16);
        ps += __shfl_xor(ps, 32);
        l = l * alpha + ps;
        m = mnew;
        #pragma unroll
        for (int i = 0; i < 4; ++i) {
            o[i][0] *= alpha; o[i][1] *= alpha; o[i][2] *= alpha; o[i][3] *= alpha;
        }
        // ---- O += V P (V frags from LDS, P^T frags from per-wave LDS)
        #pragma unroll
        for (int s = 0; s < 2; ++s) {
            s8v pf = *(const s8v*)&pt[r][s * 32 + quad * 8];
            #pragma unroll
            for (int i = 0; i < 4; ++i) {
                s8v vf = *(const s8v*)&Vs[buf][(16 * i + r) * 64 + s * 32 + quad * 8];
                o[i] = __builtin_amdgcn_mfma_f32_16x16x32_bf16(vf, pf, o[i], 0, 0, 0);
            }
        }
        buf ^= 1;
    }

    const float inv = 1.0f / (l * 32.0f);
    #pragma unroll
    for (int i = 0; i < 4; ++i)
        #pragma unroll
        for (int reg = 0; reg < 4; ++reg)
            Ao[(size_t)(bh * 64 + 16 * i + quad * 4 + reg) * Wn + kcol] = o[i][reg] * inv;
}

// ---------------------------------------------------------------------------
// fp32 fallback GEMM + attention (round-2 proven).
// ---------------------------------------------------------------------------
__global__ __launch_bounds__(256, 2)
void gemm128(const float* __restrict__ L, const float* __restrict__ X,
             float* __restrict__ Y, const float* __restrict__ bias) {
    __shared__ float As[16][132];
    __shared__ float Bs[16][132];

    const int bz = blockIdx.z;
    const float* Xb = X + (size_t)bz * En * Wn;
    float*       Yb = Y + (size_t)bz * En * Wn;
    const int e0 = blockIdx.y * 128;
    const int w0 = blockIdx.x * 128;
    const int t  = threadIdx.x;
    const int tx = t & 15, ty = t >> 4;
    const int la_e = t >> 2, la_f = (t & 3) << 2;
    const int lb_f = t >> 5, lb_w = (t & 31) << 2;

    float acc[2][2][4][4] = {};

    for (int f0 = 0; f0 < En; f0 += 16) {
        f4 a0 = *(const f4*)&L [(size_t)(e0 + la_e)      * En + f0 + la_f];
        f4 a1 = *(const f4*)&L [(size_t)(e0 + la_e + 64) * En + f0 + la_f];
        f4 b0 = *(const f4*)&Xb[(size_t)(f0 + lb_f)      * Wn + w0 + lb_w];
        f4 b1 = *(const f4*)&Xb[(size_t)(f0 + lb_f + 8)  * Wn + w0 + lb_w];
        __syncthreads();
        As[la_f + 0][la_e] = a0[0]; As[la_f + 1][la_e] = a0[1];
        As[la_f + 2][la_e] = a0[2]; As[la_f + 3][la_e] = a0[3];
        As[la_f + 0][la_e + 64] = a1[0]; As[la_f + 1][la_e + 64] = a1[1];
        As[la_f + 2][la_e + 64] = a1[2]; As[la_f + 3][la_e + 64] = a1[3];
        *(f4*)&Bs[lb_f    ][lb_w] = b0;
        *(f4*)&Bs[lb_f + 8][lb_w] = b1;
        __syncthreads();
        #pragma unroll
        for (int kk = 0; kk < 16; ++kk) {
            f4 av0 = *(f4*)&As[kk][ty * 4];
            f4 av1 = *(f4*)&As[kk][ty * 4 + 64];
            f4 bv0 = *(f4*)&Bs[kk][tx * 4];
            f4 bv1 = *(f4*)&Bs[kk][tx * 4 + 64];
            #pragma unroll
            for (int i = 0; i < 4; ++i)
                #pragma unroll
                for (int j = 0; j < 4; ++j) {
                    acc[0][0][i][j] = fmaf(av0[i], bv0[j], acc[0][0][i][j]);
                    acc[0][1][i][j] = fmaf(av0[i], bv1[j], acc[0][1][i][j]);
                    acc[1][0][i][j] = fmaf(av1[i], bv0[j], acc[1][0][i][j]);
                    acc[1][1][i][j] = fmaf(av1[i], bv1[j], acc[1][1][i][j]);
                }
        }
    }

    #pragma unroll
    for (int eh = 0; eh < 2; ++eh)
        #pragma unroll
        for (int i = 0; i < 4; ++i) {
            const int e = e0 + eh * 64 + ty * 4 + i;
            const float bv = bias ? bias[e] : 0.0f;
            #pragma unroll
            for (int wh = 0; wh < 2; ++wh) {
                f4 v;
                #pragma unroll
                for (int j = 0; j < 4; ++j) v[j] = acc[eh][wh][i][j] + bv;
                *(f4*)&Yb[(size_t)e * Wn + w0 + wh * 64 + tx * 4] = v;
            }
        }
}

__global__ __launch_bounds__(256, 2)
void attn64(const float* __restrict__ Qg, const float* __restrict__ Kg,
            const float* __restrict__ Vg, float* __restrict__ Og) {
    __shared__ float Ks[64][68];
    __shared__ float QP[64][68];
    __shared__ float Vt[64][68];
    __shared__ float mArr[64], lArr[64], alphaArr[64];
    __shared__ float red[4][64];

    const int kb = blockIdx.x, h = blockIdx.y, b = blockIdx.z;
    const size_t base = ((size_t)b * En + (size_t)h * DHn) * Wn;
    const float* Qp = Qg + base;
    const float* Kp = Kg + base;
    const float* Vp = Vg + base;
    float*       Op = Og + base;

    const int t  = threadIdx.x;
    const int tx = t & 15, ty = t >> 4;
    const int lr = t >> 4;
    const int lc = (t & 15) << 2;
    const int k0 = kb * 64;
    const int kc = t & 63, qg = t >> 6;

    #pragma unroll
    for (int r = 0; r < 4; ++r)
        *(f4*)&Ks[lr + r * 16][lc] =
            *(const f4*)&Kp[(size_t)(lr + r * 16) * Wn + k0 + lc];
    if (t < 64) { mArr[t] = -1e30f; lArr[t] = 0.0f; }
    float acc[4][4] = {};
    __syncthreads();

    for (int q0 = 0; q0 <= k0; q0 += 64) {
        #pragma unroll
        for (int r = 0; r < 4; ++r) {
            const int d = lr + r * 16;
            f4 qv = *(const f4*)&Qp[(size_t)d * Wn + q0 + lc];
            f4 vv = *(const f4*)&Vp[(size_t)d * Wn + q0 + lc];
            *(f4*)&QP[d][lc] = qv;
            Vt[lc + 0][d] = vv[0]; Vt[lc + 1][d] = vv[1];
            Vt[lc + 2][d] = vv[2]; Vt[lc + 3][d] = vv[3];
        }
        __syncthreads();

        float s[4][4] = {};
        #pragma unroll 4
        for (int d = 0; d < 64; ++d) {
            f4 kv = *(f4*)&Ks[d][tx * 4];
            f4 q2 = *(f4*)&QP[d][ty * 4];
            #pragma unroll
            for (int i = 0; i < 4; ++i)
                #pragma unroll
                for (int j = 0; j < 4; ++j)
                    s[i][j] = fmaf(q2[i], kv[j], s[i][j]);
        }
        if (q0 == k0) {
            #pragma unroll
            for (int i = 0; i < 4; ++i)
                #pragma unroll
                for (int j = 0; j < 4; ++j)
                    if (ty * 4 + i > tx * 4 + j) s[i][j] = -1e30f;
        }
        __syncthreads();
        #pragma unroll
        for (int i = 0; i < 4; ++i) {
            f4 v;
            #pragma unroll
            for (int j = 0; j < 4; ++j) v[j] = s[i][j];
            *(f4*)&QP[ty * 4 + i][tx * 4] = v;
        }
        __syncthreads();

        float sv[16];
        float lm = -1e30f;
        #pragma unroll
        for (int r = 0; r < 16; ++r) {
            sv[r] = QP[qg * 16 + r][kc];
            lm = fmaxf(lm, sv[r]);
        }
        red[qg][kc] = lm;
        __syncthreads();
        const float mt    = fmaxf(fmaxf(red[0][kc], red[1][kc]),
                                  fmaxf(red[2][kc], red[3][kc]));
        const float mprev = mArr[kc];
        const float mnew  = fmaxf(mprev, mt);
        float psum = 0.0f;
        #pragma unroll
        for (int r = 0; r < 16; ++r) {
            const float p = __expf(sv[r] - mnew);
            psum += p;
            QP[qg * 16 + r][kc] = p;
        }
        __syncthreads();
        red[qg][kc] = psum;
        __syncthreads();
        if (qg == 0) {
            const float alpha = __expf(mprev - mnew);
            lArr[kc] = lArr[kc] * alpha +
                       (red[0][kc] + red[1][kc] + red[2][kc] + red[3][kc]);
            mArr[kc]     = mnew;
            alphaArr[kc] = alpha;
        }
        __syncthreads();

        f4 al = *(f4*)&alphaArr[tx * 4];
        #pragma unroll
        for (int i = 0; i < 4; ++i)
            #pragma unroll
            for (int j = 0; j < 4; ++j)
                acc[i][j] *= al[j];
        #pragma unroll 4
        for (int q = 0; q < 64; ++q) {
            f4 pv = *(f4*)&QP[q][tx * 4];
            f4 v2 = *(f4*)&Vt[q][ty * 4];
            #pragma unroll
            for (int i = 0; i < 4; ++i)
                #pragma unroll
                for (int j = 0; j < 4; ++j)
                    acc[i][j] = fmaf(v2[i], pv[j], acc[i][j]);
        }
        __syncthreads();
    }

    f4 linv = *(f4*)&lArr[tx * 4];
    #pragma unroll
    for (int j = 0; j < 4; ++j) linv[j] = 1.0f / (linv[j] * 32.0f);
    #pragma unroll
    for (int i = 0; i < 4; ++i) {
        f4 v;
        #pragma unroll
        for (int j = 0; j < 4; ++j) v[j] = acc[i][j] * linv[j];
        *(f4*)&Op[(size_t)(ty * 4 + i) * Wn + k0 + tx * 4] = v;
    }
}

// ---------------------------------------------------------------------------
extern "C" void kernel_launch(void* const* d_in, const int* in_sizes, int n_in,
                              void* d_out, int out_size, void* d_ws, size_t ws_size,
                              hipStream_t stream) {
    const float* x    = (const float*)d_in[0];   // [3,B,E,W]: x[0]=K, x[1]=Q, x[2]=V
    const float* L_Q  = (const float*)d_in[1];
    const float* L_K  = (const float*)d_in[2];
    const float* L_V  = (const float*)d_in[3];
    const float* M    = (const float*)d_in[4];
    const float* bias = (const float*)d_in[5];
    float* out = (float*)d_out;

    const size_t mat   = (size_t)Bn * En * Wn;       // 8M elements
    const size_t matB  = mat * 4;                    // 33,554,432 bytes
    const size_t lmatB = (size_t)En * En * 2;        // 2 MB per bf16 L piece
    const size_t need  = 8 * lmatB + 5 * matB;       // 184,549,376 B (proven fit)

    if (ws_size >= need) {
        char* w = (char*)d_ws;
        u16*  Lsp = (u16*)w;                         // 16 MB, 8 pieces
        char* XT  = w + 8 * lmatB;                   // x^T splits, later Ao^T
        char* RC  = XT + matB;                       // Kp fp32 -> QT hi/lo
        char* RD  = RC + matB;                       // Qp fp32 -> Vb bf16
        char* RE  = RD + matB;                       // Vp fp32 -> Ao fp32
        char* RF  = RE + matB;                       // KT hi/lo

        u16* LKh = Lsp + 0 * (lmatB / 2); u16* LKl = Lsp + 1 * (lmatB / 2);
        u16* LQh = Lsp + 2 * (lmatB / 2); u16* LQl = Lsp + 3 * (lmatB / 2);
        u16* LVh = Lsp + 4 * (lmatB / 2); u16* LVl = Lsp + 5 * (lmatB / 2);
        u16* Mh  = Lsp + 6 * (lmatB / 2); u16* Ml  = Lsp + 7 * (lmatB / 2);

        u16* XT_H = (u16*)XT;          u16* XT_L = (u16*)(XT + matB / 2);
        float* Kp = (float*)RC;
        u16* KT_h = (u16*)RF;          u16* KT_l = (u16*)(RF + matB / 2);
        float* Qp = (float*)RD;
        u16* QT_h = (u16*)RC;          u16* QT_l = (u16*)(RC + matB / 2);
        float* Vp = (float*)RE;
        u16* Vb   = (u16*)RD;
        float* Ao = (float*)RE;

        const int n4L = En * En / 4;
        hipLaunchKernelGGL(split_plain, dim3(n4L / 256), dim3(256), 0, stream, L_K, LKh, LKl, n4L);
        hipLaunchKernelGGL(split_plain, dim3(n4L / 256), dim3(256), 0, stream, L_Q, LQh, LQl, n4L);
        hipLaunchKernelGGL(split_plain, dim3(n4L / 256), dim3(256), 0, stream, L_V, LVh, LVl, n4L);
        hipLaunchKernelGGL(split_plain, dim3(n4L / 256), dim3(256), 0, stream, M,   Mh,  Ml,  n4L);

        dim3 gt(Wn / 32, En / 32, Bn), bt(256);
        dim3 gg(Wn / 128, En / 128, Bn), bg(256);
        dim3 gr(Wn / 64, Bn * Hn);

        // K = L_K @ x[0]; repack -> KT
        hipLaunchKernelGGL(split_t, gt, bt, 0, stream, x + 0 * mat, XT_H, XT_L);
        hipLaunchKernelGGL(gemm_mfma, gg, bg, 0, stream, LKh, LKl, XT_H, XT_L, Kp, (const float*)nullptr);
        hipLaunchKernelGGL(qk_repack, gr, dim3(256), 0, stream, Kp, KT_h, KT_l);
        // Q = L_Q @ x[1]; repack -> QT (into Kp region)
        hipLaunchKernelGGL(split_t, gt, bt, 0, stream, x + 1 * mat, XT_H, XT_L);
        hipLaunchKernelGGL(gemm_mfma, gg, bg, 0, stream, LQh, LQl, XT_H, XT_L, Qp, (const float*)nullptr);
        hipLaunchKernelGGL(qk_repack, gr, dim3(256), 0, stream, Qp, QT_h, QT_l);
        // V = L_V @ x[2]; cast -> Vb (into Qp region)
        hipLaunchKernelGGL(split_t, gt, bt, 0, stream, x + 2 * mat, XT_H, XT_L);
        hipLaunchKernelGGL(gemm_mfma, gg, bg, 0, stream, LVh, LVl, XT_H, XT_L, Vp, (const float*)nullptr);
        hipLaunchKernelGGL(f32_to_bf16, dim3((int)(mat / 4 / 256)), dim3(256), 0, stream, Vp, Vb, (int)(mat / 4));

        // attention -> Ao (into Vp region); 1-D XCD-swizzled grid
        hipLaunchKernelGGL(attn_mfma2, dim3(2048), dim3(256), 0, stream,
                           QT_h, QT_l, KT_h, KT_l, Vb, Ao);

        // out = M @ Ao + b
        hipLaunchKernelGGL(split_t, gt, bt, 0, stream, Ao, XT_H, XT_L);
        hipLaunchKernelGGL(gemm_mfma, gg, bg, 0, stream, Mh, Ml, XT_H, XT_L, out, bias);
    } else {
        // fallback: fp32 path (needs 4*matB = 134 MB)
        float* ws = (float*)d_ws;
        float* Kp = ws;
        float* Qp = ws + mat;
        float* Vp = ws + 2 * mat;
        float* Ao = ws + 3 * mat;

        dim3 gg(Wn / 128, En / 128, Bn), blk(256);
        hipLaunchKernelGGL(gemm128, gg, blk, 0, stream, L_K, x + 0 * mat, Kp, (const float*)nullptr);
        hipLaunchKernelGGL(gemm128, gg, blk, 0, stream, L_Q, x + 1 * mat, Qp, (const float*)nullptr);
        hipLaunchKernelGGL(gemm128, gg, blk, 0, stream, L_V, x + 2 * mat, Vp, (const float*)nullptr);

        dim3 ga(Wn / 64, Hn, Bn);
        hipLaunchKernelGGL(attn64, ga, blk, 0, stream, Qp, Kp, Vp, Ao);

        hipLaunchKernelGGL(gemm128, gg, blk, 0, stream, M, Ao, out, bias);
    }
}